// Round 2
// baseline (154.415 us; speedup 1.0000x reference)
//
#include <hip/hip_runtime.h>
#include <hip/hip_bf16.h>
#include <stdint.h>

#define T_DIM 1024
#define B_DIM 8

typedef __attribute__((ext_vector_type(8))) short short8;
typedef __attribute__((ext_vector_type(4))) float f32x4;

__device__ inline void gll16(const void* g, void* l) {
  __builtin_amdgcn_global_load_lds((__attribute__((address_space(1))) void*)g,
                                   (__attribute__((address_space(3))) void*)l,
                                   16, 0, 0);
}

// ---------------- fp32 -> bf16 convert ----------------
__global__ __launch_bounds__(256) void convert_kernel(const float* __restrict__ F,
                                                      __hip_bfloat16* __restrict__ Fb) {
  const int t = blockIdx.x * 256 + threadIdx.x;
  const float4 v = ((const float4*)F)[t];
  union { __hip_bfloat16 h[4]; uint64_t u; } p;
  p.h[0] = __float2bfloat16(v.x);
  p.h[1] = __float2bfloat16(v.y);
  p.h[2] = __float2bfloat16(v.z);
  p.h[3] = __float2bfloat16(v.w);
  ((uint64_t*)Fb)[t] = p.u;
}

// ---------------- fused Gram + row-partial kernel ----------------
// Per block: one 128x128 tile of S = 10*(F F^T) for batch b, computed with
// bf16 MFMA (double-buffered global_load_lds staging, BK=64), then an epilogue
// that produces per-row online-softmax partials (m, den, msum, cnt, bad)
// over this tile's 128 columns. S is never materialized.
// partial layout: part[b][row(1024)][slot ct(8)][5]
__global__ __launch_bounds__(256) void fused_kernel(const __hip_bfloat16* __restrict__ Fb,
                                                    const float* __restrict__ M,
                                                    const int* __restrict__ icl,
                                                    float* __restrict__ part) {
  const int b  = blockIdx.z;
  const int rt = blockIdx.y;
  const int ct = blockIdx.x;
  const int L  = icl[b] + 1;
  if (rt * 128 >= L || ct * 128 >= L) return;   // tile fully invalid

  // LDS: double-buffered A/B tiles (128x64 bf16, sub-tiled in 32-col halves)
  __shared__ __hip_bfloat16 As[2][8192];
  __shared__ __hip_bfloat16 Bs[2][8192];
  __shared__ float rp_m[128][2], rp_d[128][2], rp_s[128][2], rp_c[128][2], rp_b[128][2];

  const __hip_bfloat16* F = Fb + ((size_t)b << 20);
  const int tid  = threadIdx.x;
  const int lane = tid & 63;
  const int wave = tid >> 6;
  const int wrow = (wave >> 1) * 64;
  const int wcol = (wave & 1) * 64;
  const int row0 = rt * 128;
  const int col0 = ct * 128;
  const bool diag = (rt == ct);

  const int fr = lane & 15;        // fragment row/col within 16
  const int q  = lane >> 4;        // quarter-wave index
  const int fk = q * 8;            // fragment k offset

  // staging addressing: pass p -> rows half*64 + (tid>>2), k-cols kk*32 + (tid&3)*8
  const int srow = tid >> 2;
  const int skc  = (tid & 3) * 8;

  f32x4 acc[4][4];
#pragma unroll
  for (int i = 0; i < 4; i++)
#pragma unroll
    for (int j = 0; j < 4; j++) acc[i][j] = (f32x4){0.f, 0.f, 0.f, 0.f};

  // ---- K loop: 16 steps of BK=64, 1-deep double buffer ----
  auto stage = [&](int buf, int k0) {
#pragma unroll
    for (int p = 0; p < 4; p++) {
      const int half = p & 1, kk = p >> 1;
      gll16(F + (size_t)(row0 + half * 64 + srow) * T_DIM + k0 + kk * 32 + skc,
            &As[buf][kk * 4096 + half * 2048 + tid * 8]);
    }
    if (!diag) {
#pragma unroll
      for (int p = 0; p < 4; p++) {
        const int half = p & 1, kk = p >> 1;
        gll16(F + (size_t)(col0 + half * 64 + srow) * T_DIM + k0 + kk * 32 + skc,
              &Bs[buf][kk * 4096 + half * 2048 + tid * 8]);
      }
    }
  };

  stage(0, 0);
  int cur = 0;
  for (int ks = 0; ks < 16; ks++) {
    __syncthreads();                       // buf[cur] ready (vmcnt drain) + prev readers done
    if (ks + 1 < 16) stage(cur ^ 1, (ks + 1) * 64);   // overlaps with compute below
#pragma unroll
    for (int kk = 0; kk < 2; kk++) {
      const __hip_bfloat16* Ab = &As[cur][kk * 4096];
      const __hip_bfloat16* Bb = diag ? Ab : &Bs[cur][kk * 4096];
      short8 af[4], bfr[4];
#pragma unroll
      for (int t = 0; t < 4; t++) {
        af[t]  = *(const short8*)(Ab + (wrow + t * 16 + fr) * 32 + fk);
        bfr[t] = *(const short8*)(Bb + (wcol + t * 16 + fr) * 32 + fk);
      }
#pragma unroll
      for (int ti = 0; ti < 4; ti++)
#pragma unroll
        for (int tj = 0; tj < 4; tj++)
          acc[ti][tj] = __builtin_amdgcn_mfma_f32_16x16x32_bf16(af[ti], bfr[tj], acc[ti][tj], 0, 0, 0);
    }
    cur ^= 1;
  }

  // ---- epilogue: per-row partials over this tile's columns ----
  // C/D layout: col = lane&15, row = (lane>>4)*4 + r  [m89-verified]
  const float* Mb = M + ((size_t)b << 20);
#pragma unroll
  for (int ti = 0; ti < 4; ti++) {
#pragma unroll
    for (int r = 0; r < 4; r++) {
      const int lrow = wrow + ti * 16 + q * 4 + r;    // 0..127
      const int grow = row0 + lrow;
      float m = -1e30f, den = 0.f, msum = 0.f, cnt = 0.f, badf = 0.f;
#pragma unroll
      for (int tj = 0; tj < 4; tj++) {
        const int gcol = col0 + wcol + tj * 16 + fr;
        if (gcol < L) {
          const float s  = acc[ti][tj][r] * 10.0f;
          const float mk = Mb[(size_t)grow * T_DIM + gcol];
          const float nm = fmaxf(m, s);
          const bool  dg = (gcol == grow);
          den = den * __expf(m - nm) + (dg ? 0.f : __expf(s - nm));
          m = nm;
          if (!dg) { msum += mk * s; cnt += mk; }
          const float sane = (dg && grow != 0) ? 1.f : 0.f;
          badf = fmaxf(badf, (mk != sane) ? 1.f : 0.f);
        }
      }
      // butterfly across the 16 lanes holding the same row (xor 1,2,4,8)
#pragma unroll
      for (int d = 1; d < 16; d <<= 1) {
        const float om  = __shfl_xor(m, d, 64);
        const float od  = __shfl_xor(den, d, 64);
        const float os  = __shfl_xor(msum, d, 64);
        const float oc  = __shfl_xor(cnt, d, 64);
        const float ob  = __shfl_xor(badf, d, 64);
        const float nm  = fmaxf(m, om);
        den = den * __expf(m - nm) + od * __expf(om - nm);
        m = nm; msum += os; cnt += oc; badf = fmaxf(badf, ob);
      }
      if (fr == 0) {
        const int h = wave & 1;                        // column half
        rp_m[lrow][h] = m;  rp_d[lrow][h] = den; rp_s[lrow][h] = msum;
        rp_c[lrow][h] = cnt; rp_b[lrow][h] = badf;
      }
    }
  }
  __syncthreads();

  // merge the two column halves, write one slot per row
  if (tid < 128) {
    const float m0 = rp_m[tid][0], m1 = rp_m[tid][1];
    const float nm = fmaxf(m0, m1);
    const float den = rp_d[tid][0] * __expf(m0 - nm) + rp_d[tid][1] * __expf(m1 - nm);
    const float msum = rp_s[tid][0] + rp_s[tid][1];
    const float cnt  = rp_c[tid][0] + rp_c[tid][1];
    const float badf = fmaxf(rp_b[tid][0], rp_b[tid][1]);
    float* p = part + ((((size_t)b * 1024 + row0 + tid) * 8) + ct) * 5;
    p[0] = nm; p[1] = den; p[2] = msum; p[3] = cnt; p[4] = badf;
  }
}

// ---------------- reduce: merge 8 column-tile slots per row ----------------
__global__ __launch_bounds__(256) void reduce_kernel(const float* __restrict__ part,
                                                     const int* __restrict__ icl,
                                                     float* __restrict__ row_val,
                                                     int* __restrict__ row_bad) {
  const int row = blockIdx.x * 256 + threadIdx.x;   // 0..8191
  const int b = row >> 10;
  const int i = row & 1023;
  const int L = icl[b] + 1;
  if (i >= L) { row_val[row] = 0.f; row_bad[row] = 0; return; }
  const float* p = part + (size_t)row * 40;
  const int ns = (L + 127) >> 7;                    // valid slots
  float m = -1e30f, den = 0.f, msum = 0.f, cnt = 0.f, badf = 0.f;
  for (int s = 0; s < ns; s++) {
    const float pm = p[s * 5 + 0], pd = p[s * 5 + 1];
    const float nm = fmaxf(m, pm);
    den = den * __expf(m - nm) + pd * __expf(pm - nm);
    m = nm;
    msum += p[s * 5 + 2]; cnt += p[s * 5 + 3]; badf = fmaxf(badf, p[s * 5 + 4]);
  }
  const float A = msum - cnt * m;                   // sum mask*(s - mx)
  const float mlpp = (A - cnt * __logf(den + 1e-6f)) / (cnt + 1e-6f);
  row_val[row] = -mlpp / (float)L;
  row_bad[row] = badf > 0.f ? 1 : 0;
}

// ---------------- finalize (single block, deterministic) ----------------
__global__ __launch_bounds__(256) void final_kernel(const float* __restrict__ row_val,
                                                    const int* __restrict__ row_bad,
                                                    float* __restrict__ out) {
  const int tid  = threadIdx.x;
  const int lane = tid & 63;
  const int wave = tid >> 6;
  __shared__ int vb[B_DIM];
  if (tid < B_DIM) vb[tid] = 0;
  __syncthreads();
  float lsum = 0.f;
  for (int idx = tid; idx < B_DIM * T_DIM; idx += 256) {
    lsum += row_val[idx];
    if (row_bad[idx]) atomicOr(&vb[idx >> 10], 1);
  }
  for (int o = 32; o > 0; o >>= 1) lsum += __shfl_down(lsum, o, 64);
  __shared__ float partl[4];
  if (lane == 0) partl[wave] = lsum;
  __syncthreads();
  if (tid == 0) {
    const float total = partl[0] + partl[1] + partl[2] + partl[3];
    int v = 0;
    for (int bb = 0; bb < B_DIM; bb++) v += (vb[bb] ? 1 : 0);
    out[0] = total / fmaxf((float)v, 1.0f);
  }
}

extern "C" void kernel_launch(void* const* d_in, const int* in_sizes, int n_in,
                              void* d_out, int out_size, void* d_ws, size_t ws_size,
                              hipStream_t stream) {
  const float* feat = (const float*)d_in[0];
  const float* mask = (const float*)d_in[1];
  const int*   icl  = (const int*)d_in[2];
  float* out = (float*)d_out;

  char* ws = (char*)d_ws;
  __hip_bfloat16* Fb = (__hip_bfloat16*)ws;                     // 16 MiB
  float* part    = (float*)(ws + (16u << 20));                  // 1.3 MiB
  float* row_val = (float*)(ws + (18u << 20));                  // 32 KiB
  int*   row_bad = (int*)(ws + (18u << 20) + (32u << 10));      // 32 KiB

  convert_kernel<<<dim3(8192), dim3(256), 0, stream>>>(feat, Fb);
  fused_kernel<<<dim3(8, 8, 8), dim3(256), 0, stream>>>(Fb, mask, icl, part);
  reduce_kernel<<<dim3(32), dim3(256), 0, stream>>>(part, icl, row_val, row_bad);
  final_kernel<<<dim3(1), dim3(256), 0, stream>>>(row_val, row_bad, out);
}

// Round 5
// 138.468 us; speedup vs baseline: 1.1152x; 1.1152x over previous
//
#include <hip/hip_runtime.h>
#include <hip/hip_bf16.h>
#include <stdint.h>

#define T_DIM 1024
#define B_DIM 8

typedef __attribute__((ext_vector_type(8))) short short8;
typedef __attribute__((ext_vector_type(4))) float f32x4;

__device__ inline void gll16(const void* g, void* l) {
  __builtin_amdgcn_global_load_lds((__attribute__((address_space(1))) void*)g,
                                   (__attribute__((address_space(3))) void*)l,
                                   16, 0, 0);
}

// ---------------- fp32 -> bf16 convert ----------------
__global__ __launch_bounds__(256) void convert_kernel(const float* __restrict__ F,
                                                      __hip_bfloat16* __restrict__ Fb) {
  const int t = blockIdx.x * 256 + threadIdx.x;
  const float4 v = ((const float4*)F)[t];
  union { __hip_bfloat16 h[4]; uint64_t u; } p;
  p.h[0] = __float2bfloat16(v.x);
  p.h[1] = __float2bfloat16(v.y);
  p.h[2] = __float2bfloat16(v.z);
  p.h[3] = __float2bfloat16(v.w);
  ((uint64_t*)Fb)[t] = p.u;
}

// ---------------- fused Gram + row-partial kernel ----------------
// 512 threads = 8 waves, tiled 2x4 over a 128x128 tile (each wave 64x32).
// Single-buffered BK=64 staging (m97 2-barrier shape). Epilogue computes
// per-row partials (m, den, msum, cnt, bad) over this tile's columns.
// partial layout: part[b][row(1024)][slot ct(8)][5]
__global__ __launch_bounds__(512) void fused_kernel(const __hip_bfloat16* __restrict__ Fb,
                                                    const float* __restrict__ M,
                                                    const int* __restrict__ icl,
                                                    float* __restrict__ part) {
  const int b  = blockIdx.z;
  const int rt = blockIdx.y;
  const int ct = blockIdx.x;
  const int L  = icl[b] + 1;
  if (rt * 128 >= L || ct * 128 >= L) return;   // tile fully invalid

  __shared__ __hip_bfloat16 As[2][4096];   // two 128x32 k-subtiles
  __shared__ __hip_bfloat16 Bs[2][4096];
  __shared__ float rp_m[128][4], rp_d[128][4], rp_s[128][4], rp_c[128][4], rp_b[128][4];

  const __hip_bfloat16* F = Fb + ((size_t)b << 20);
  const int tid  = threadIdx.x;
  const int lane = tid & 63;
  const int wave = tid >> 6;            // 0..7
  const int wrow = (wave >> 2) * 64;    // 0 / 64
  const int wcol = (wave & 3) * 32;     // 0 / 32 / 64 / 96
  const int row0 = rt * 128;
  const int col0 = ct * 128;
  const bool diag = (rt == ct);

  const int fr = lane & 15;             // fragment row/col within 16
  const int q  = lane >> 4;             // quarter-wave
  const int fk = q * 8;                 // fragment k offset

  // staging: 512 threads x 16B = one full 128x32 subtile per gll16 round
  const int sr = tid >> 2;              // 0..127
  const int sk = (tid & 3) * 8;         // 0,8,16,24

  f32x4 acc[4][2];
#pragma unroll
  for (int i = 0; i < 4; i++)
#pragma unroll
    for (int j = 0; j < 2; j++) acc[i][j] = (f32x4){0.f, 0.f, 0.f, 0.f};

  for (int k0 = 0; k0 < T_DIM; k0 += 64) {
    __syncthreads();                    // previous iter's LDS readers done
    gll16(F + (size_t)(row0 + sr) * T_DIM + k0 + sk,      &As[0][tid * 8]);
    gll16(F + (size_t)(row0 + sr) * T_DIM + k0 + 32 + sk, &As[1][tid * 8]);
    if (!diag) {
      gll16(F + (size_t)(col0 + sr) * T_DIM + k0 + sk,      &Bs[0][tid * 8]);
      gll16(F + (size_t)(col0 + sr) * T_DIM + k0 + 32 + sk, &Bs[1][tid * 8]);
    }
    __syncthreads();                    // vmcnt drained -> LDS populated
#pragma unroll
    for (int kk = 0; kk < 2; kk++) {
      const __hip_bfloat16* Ab = As[kk];
      const __hip_bfloat16* Bb = diag ? As[kk] : Bs[kk];
      short8 af[4], bfr[2];
#pragma unroll
      for (int t = 0; t < 4; t++)
        af[t] = *(const short8*)(Ab + (wrow + t * 16 + fr) * 32 + fk);
#pragma unroll
      for (int j = 0; j < 2; j++)
        bfr[j] = *(const short8*)(Bb + (wcol + j * 16 + fr) * 32 + fk);
#pragma unroll
      for (int ti = 0; ti < 4; ti++)
#pragma unroll
        for (int tj = 0; tj < 2; tj++)
          acc[ti][tj] = __builtin_amdgcn_mfma_f32_16x16x32_bf16(af[ti], bfr[tj], acc[ti][tj], 0, 0, 0);
    }
  }

  // ---- epilogue ----
  // C/D layout: col = lane&15, row = (lane>>4)*4 + r  [m89-verified]
  const float* Mb = M + ((size_t)b << 20);
  const int gc0 = col0 + wcol + fr;
  const int gc1 = gc0 + 16;
#pragma unroll
  for (int ti = 0; ti < 4; ti++) {
#pragma unroll
    for (int r = 0; r < 4; r++) {
      const int lrow = wrow + ti * 16 + q * 4 + r;    // 0..127
      const int grow = row0 + lrow;
      const float s0 = (gc0 < L) ? acc[ti][0][r] * 10.0f : -1e30f;
      const float s1 = (gc1 < L) ? acc[ti][1][r] * 10.0f : -1e30f;
      // max over the 32 columns this 16-lane group owns (diag included)
      float m = fmaxf(s0, s1);
#pragma unroll
      for (int d = 1; d < 16; d <<= 1) m = fmaxf(m, __shfl_xor(m, d, 64));
      float den = 0.f, msum = 0.f, cnt = 0.f, badf = 0.f;
      if (gc0 < L) {
        const float mk = Mb[(size_t)grow * T_DIM + gc0];
        if (gc0 != grow) { den += __expf(s0 - m); msum += mk * s0; cnt += mk; }
        const float sane = (gc0 == grow && grow != 0) ? 1.f : 0.f;
        badf = fmaxf(badf, (mk != sane) ? 1.f : 0.f);
      }
      if (gc1 < L) {
        const float mk = Mb[(size_t)grow * T_DIM + gc1];
        if (gc1 != grow) { den += __expf(s1 - m); msum += mk * s1; cnt += mk; }
        const float sane = (gc1 == grow && grow != 0) ? 1.f : 0.f;
        badf = fmaxf(badf, (mk != sane) ? 1.f : 0.f);
      }
#pragma unroll
      for (int d = 1; d < 16; d <<= 1) {
        den  += __shfl_xor(den, d, 64);
        msum += __shfl_xor(msum, d, 64);
        cnt  += __shfl_xor(cnt, d, 64);
        badf  = fmaxf(badf, __shfl_xor(badf, d, 64));
      }
      if (fr == 0) {
        const int slot = wave & 3;
        rp_m[lrow][slot] = m;   rp_d[lrow][slot] = den;
        rp_s[lrow][slot] = msum; rp_c[lrow][slot] = cnt;
        rp_b[lrow][slot] = badf;
      }
    }
  }
  __syncthreads();

  if (tid < 128) {
    float m = -1e30f;
#pragma unroll
    for (int s = 0; s < 4; s++) m = fmaxf(m, rp_m[tid][s]);
    float den = 0.f, msum = 0.f, cnt = 0.f, badf = 0.f;
#pragma unroll
    for (int s = 0; s < 4; s++) {
      den  += rp_d[tid][s] * __expf(rp_m[tid][s] - m);   // empty slots: 0 * 0
      msum += rp_s[tid][s];
      cnt  += rp_c[tid][s];
      badf  = fmaxf(badf, rp_b[tid][s]);
    }
    float* p = part + ((((size_t)b * 1024 + row0 + tid) * 8) + ct) * 5;
    p[0] = m; p[1] = den; p[2] = msum; p[3] = cnt; p[4] = badf;
  }
}

// ---------------- reduce: merge 8 column-tile slots per row ----------------
// 32 blocks x 256 rows; emits one partial sum + bad flag per block.
__global__ __launch_bounds__(256) void reduce_kernel(const float* __restrict__ part,
                                                     const int* __restrict__ icl,
                                                     float* __restrict__ blk_sum,
                                                     int* __restrict__ blk_bad) {
  const int blk = blockIdx.x;
  const int row = blk * 256 + threadIdx.x;   // 0..8191
  const int b = row >> 10;
  const int i = row & 1023;
  const int L = icl[b] + 1;
  float rv = 0.f;
  int bad = 0;
  if (i < L) {
    const float* p = part + (size_t)row * 40;
    const int ns = (L + 127) >> 7;           // valid slots
    float m = -1e30f;
    for (int s = 0; s < ns; s++) m = fmaxf(m, p[s * 5 + 0]);
    float den = 0.f, msum = 0.f, cnt = 0.f, badf = 0.f;
    for (int s = 0; s < ns; s++) {
      den  += p[s * 5 + 1] * __expf(p[s * 5 + 0] - m);
      msum += p[s * 5 + 2];
      cnt  += p[s * 5 + 3];
      badf  = fmaxf(badf, p[s * 5 + 4]);
    }
    const float A = msum - cnt * m;          // sum mask*(s - mx)
    const float mlpp = (A - cnt * __logf(den + 1e-6f)) / (cnt + 1e-6f);
    rv = -mlpp / (float)L;
    bad = badf > 0.f ? 1 : 0;
  }
  const int tid  = threadIdx.x;
  const int lane = tid & 63;
  const int wave = tid >> 6;
  for (int o = 32; o > 0; o >>= 1) rv += __shfl_down(rv, o, 64);
  const int wbad = (__ballot(bad) != 0ull) ? 1 : 0;
  __shared__ float sred[4];
  __shared__ int bred[4];
  if (lane == 0) { sred[wave] = rv; bred[wave] = wbad; }
  __syncthreads();
  if (tid == 0) {
    blk_sum[blk] = sred[0] + sred[1] + sred[2] + sred[3];
    blk_bad[blk] = bred[0] | bred[1] | bred[2] | bred[3];
  }
}

// ---------------- finalize (single wave, deterministic) ----------------
__global__ __launch_bounds__(64) void final_kernel(const float* __restrict__ blk_sum,
                                                   const int* __restrict__ blk_bad,
                                                   float* __restrict__ out) {
  const int tid = threadIdx.x;
  float v = (tid < 32) ? blk_sum[tid] : 0.f;
  for (int o = 32; o > 0; o >>= 1) v += __shfl_down(v, o, 64);
  if (tid == 0) {
    int vcount = 0;
    for (int bb = 0; bb < B_DIM; bb++) {
      const int any = blk_bad[bb * 4] | blk_bad[bb * 4 + 1] |
                      blk_bad[bb * 4 + 2] | blk_bad[bb * 4 + 3];
      vcount += any ? 1 : 0;
    }
    out[0] = v / fmaxf((float)vcount, 1.0f);
  }
}

extern "C" void kernel_launch(void* const* d_in, const int* in_sizes, int n_in,
                              void* d_out, int out_size, void* d_ws, size_t ws_size,
                              hipStream_t stream) {
  const float* feat = (const float*)d_in[0];
  const float* mask = (const float*)d_in[1];
  const int*   icl  = (const int*)d_in[2];
  float* out = (float*)d_out;

  char* ws = (char*)d_ws;
  __hip_bfloat16* Fb = (__hip_bfloat16*)ws;                 // 16 MiB
  float* part    = (float*)(ws + (16u << 20));              // 1.31 MiB
  float* blk_sum = (float*)(ws + (18u << 20));              // 128 B
  int*   blk_bad = (int*)(ws + (18u << 20) + 512);          // 128 B

  convert_kernel<<<dim3(8192), dim3(256), 0, stream>>>(feat, Fb);
  fused_kernel<<<dim3(8, 8, 8), dim3(512), 0, stream>>>(Fb, mask, icl, part);
  reduce_kernel<<<dim3(32), dim3(256), 0, stream>>>(part, icl, blk_sum, blk_bad);
  final_kernel<<<dim3(1), dim3(64), 0, stream>>>(blk_sum, blk_bad, out);
}

// Round 6
// 134.018 us; speedup vs baseline: 1.1522x; 1.0332x over previous
//
#include <hip/hip_runtime.h>
#include <hip/hip_bf16.h>
#include <stdint.h>

#define T_DIM 1024
#define B_DIM 8

typedef __attribute__((ext_vector_type(8))) short short8;
typedef __attribute__((ext_vector_type(4))) float f32x4;

__device__ inline void gll16(const void* g, void* l) {
  __builtin_amdgcn_global_load_lds((__attribute__((address_space(1))) void*)g,
                                   (__attribute__((address_space(3))) void*)l,
                                   16, 0, 0);
}

// ---------------- fp32 -> bf16 convert ----------------
__global__ __launch_bounds__(256) void convert_kernel(const float* __restrict__ F,
                                                      __hip_bfloat16* __restrict__ Fb) {
  const int t = blockIdx.x * 256 + threadIdx.x;
  const float4 v = ((const float4*)F)[t];
  union { __hip_bfloat16 h[4]; uint64_t u; } p;
  p.h[0] = __float2bfloat16(v.x);
  p.h[1] = __float2bfloat16(v.y);
  p.h[2] = __float2bfloat16(v.z);
  p.h[3] = __float2bfloat16(v.w);
  ((uint64_t*)Fb)[t] = p.u;
}

// ---------------- fused Gram + row-partial kernel ----------------
// 512 threads = 8 waves (2x4 wave grid) on a 128x128 tile. BK=128 (8 K-iters,
// 2-barrier m97 shape). LDS layout XOR-swizzled (slot = g ^ ((row>>1)&3)) via
// source permutation so fragment ds_read_b128 is bank-conflict-free; the
// staging gll16 dest stays lane-contiguous as required. rp arrays alias the
// staging LDS (used only after the K-loop).
// partial layout: part[b][row(1024)][slot ct(8)][5]
__global__ __launch_bounds__(512) void fused_kernel(const __hip_bfloat16* __restrict__ Fb,
                                                    const float* __restrict__ M,
                                                    const int* __restrict__ icl,
                                                    float* __restrict__ part) {
  const int b  = blockIdx.z;
  const int rt = blockIdx.y;
  const int ct = blockIdx.x;
  const int L  = icl[b] + 1;
  if (rt * 128 >= L || ct * 128 >= L) return;   // tile fully invalid

  __shared__ char smem[65536];
  __hip_bfloat16* As = (__hip_bfloat16*)smem;            // 4 panels x 128x32 = 32 KB
  __hip_bfloat16* Bs = (__hip_bfloat16*)(smem + 32768);  // 32 KB
  float* rp = (float*)smem;  // reused after K-loop: 5 arrays of 128x4 floats
  float* rp_m = rp;          // [row*4 + slot]
  float* rp_d = rp + 512;
  float* rp_s = rp + 1024;
  float* rp_c = rp + 1536;
  float* rp_b = rp + 2048;

  const __hip_bfloat16* F = Fb + ((size_t)b << 20);
  const int tid  = threadIdx.x;
  const int lane = tid & 63;
  const int wave = tid >> 6;            // 0..7
  const int wrow = (wave >> 2) * 64;    // 0 / 64
  const int wcol = (wave & 3) * 32;     // 0 / 32 / 64 / 96
  const int row0 = rt * 128;
  const int col0 = ct * 128;
  const bool diag = (rt == ct);

  const int fr = lane & 15;             // fragment row/col within 16
  const int q  = lane >> 4;             // quarter-wave (k-granule wanted)
  const int sl8 = (q ^ ((fr >> 1) & 3)) * 8;   // swizzled slot (elements)

  // staging: thread l -> LDS row l>>2, slot l&3; source granule = swizzle^-1
  const int srow = tid >> 2;                                  // 0..127
  const int sgk  = (((tid & 3) ^ ((tid >> 3) & 3)) * 8);      // source k offset

  f32x4 acc[4][2];
#pragma unroll
  for (int i = 0; i < 4; i++)
#pragma unroll
    for (int j = 0; j < 2; j++) acc[i][j] = (f32x4){0.f, 0.f, 0.f, 0.f};

  for (int k0 = 0; k0 < T_DIM; k0 += 128) {
    __syncthreads();                    // previous iter's LDS readers done
#pragma unroll
    for (int p = 0; p < 4; p++)
      gll16(F + (size_t)(row0 + srow) * T_DIM + k0 + p * 32 + sgk,
            As + p * 4096 + tid * 8);
    if (!diag) {
#pragma unroll
      for (int p = 0; p < 4; p++)
        gll16(F + (size_t)(col0 + srow) * T_DIM + k0 + p * 32 + sgk,
              Bs + p * 4096 + tid * 8);
    }
    __syncthreads();                    // vmcnt drained -> LDS populated
#pragma unroll
    for (int kk = 0; kk < 4; kk++) {
      const __hip_bfloat16* Ab = As + kk * 4096;
      const __hip_bfloat16* Bb = diag ? Ab : (Bs + kk * 4096);
      short8 af[4], bfr[2];
#pragma unroll
      for (int t = 0; t < 4; t++)
        af[t] = *(const short8*)(Ab + (wrow + t * 16 + fr) * 32 + sl8);
#pragma unroll
      for (int j = 0; j < 2; j++)
        bfr[j] = *(const short8*)(Bb + (wcol + j * 16 + fr) * 32 + sl8);
#pragma unroll
      for (int ti = 0; ti < 4; ti++)
#pragma unroll
        for (int tj = 0; tj < 2; tj++)
          acc[ti][tj] = __builtin_amdgcn_mfma_f32_16x16x32_bf16(af[ti], bfr[tj], acc[ti][tj], 0, 0, 0);
    }
  }
  __syncthreads();   // all frag reads done before rp aliases the staging LDS

  // ---- epilogue ----
  // C/D layout: col = lane&15, row = (lane>>4)*4 + r  [m89-verified]
  const float* Mb = M + ((size_t)b << 20);
  const int gc0 = col0 + wcol + fr;
  const int gc1 = gc0 + 16;
#pragma unroll
  for (int ti = 0; ti < 4; ti++) {
    // hoist the 8 mask loads for this ti-group so they pipeline
    float mk0[4], mk1[4];
#pragma unroll
    for (int r = 0; r < 4; r++) {
      const int grow = row0 + wrow + ti * 16 + q * 4 + r;
      mk0[r] = (gc0 < L) ? Mb[(size_t)grow * T_DIM + gc0] : 0.f;
      mk1[r] = (gc1 < L) ? Mb[(size_t)grow * T_DIM + gc1] : 0.f;
    }
#pragma unroll
    for (int r = 0; r < 4; r++) {
      const int lrow = wrow + ti * 16 + q * 4 + r;    // 0..127
      const int grow = row0 + lrow;
      const float s0 = (gc0 < L) ? acc[ti][0][r] * 10.0f : -1e30f;
      const float s1 = (gc1 < L) ? acc[ti][1][r] * 10.0f : -1e30f;
      float m = fmaxf(s0, s1);
#pragma unroll
      for (int d = 1; d < 16; d <<= 1) m = fmaxf(m, __shfl_xor(m, d, 64));
      float den = 0.f, msum = 0.f, cnt = 0.f, badf = 0.f;
      if (gc0 < L) {
        if (gc0 != grow) { den += __expf(s0 - m); msum += mk0[r] * s0; cnt += mk0[r]; }
        const float sane = (gc0 == grow && grow != 0) ? 1.f : 0.f;
        badf = fmaxf(badf, (mk0[r] != sane) ? 1.f : 0.f);
      }
      if (gc1 < L) {
        if (gc1 != grow) { den += __expf(s1 - m); msum += mk1[r] * s1; cnt += mk1[r]; }
        const float sane = (gc1 == grow && grow != 0) ? 1.f : 0.f;
        badf = fmaxf(badf, (mk1[r] != sane) ? 1.f : 0.f);
      }
#pragma unroll
      for (int d = 1; d < 16; d <<= 1) {
        den  += __shfl_xor(den, d, 64);
        msum += __shfl_xor(msum, d, 64);
        cnt  += __shfl_xor(cnt, d, 64);
        badf  = fmaxf(badf, __shfl_xor(badf, d, 64));
      }
      if (fr == 0) {
        const int slot = wave & 3;
        rp_m[lrow * 4 + slot] = m;   rp_d[lrow * 4 + slot] = den;
        rp_s[lrow * 4 + slot] = msum; rp_c[lrow * 4 + slot] = cnt;
        rp_b[lrow * 4 + slot] = badf;
      }
    }
  }
  __syncthreads();

  if (tid < 128) {
    float m = -1e30f;
#pragma unroll
    for (int s = 0; s < 4; s++) m = fmaxf(m, rp_m[tid * 4 + s]);
    float den = 0.f, msum = 0.f, cnt = 0.f, badf = 0.f;
#pragma unroll
    for (int s = 0; s < 4; s++) {
      den  += rp_d[tid * 4 + s] * __expf(rp_m[tid * 4 + s] - m);   // empty: 0*0
      msum += rp_s[tid * 4 + s];
      cnt  += rp_c[tid * 4 + s];
      badf  = fmaxf(badf, rp_b[tid * 4 + s]);
    }
    float* p = part + ((((size_t)b * 1024 + row0 + tid) * 8) + ct) * 5;
    p[0] = m; p[1] = den; p[2] = msum; p[3] = cnt; p[4] = badf;
  }
}

// ---------------- reduce: merge 8 column-tile slots per row ----------------
__global__ __launch_bounds__(256) void reduce_kernel(const float* __restrict__ part,
                                                     const int* __restrict__ icl,
                                                     float* __restrict__ blk_sum,
                                                     int* __restrict__ blk_bad) {
  const int blk = blockIdx.x;
  const int row = blk * 256 + threadIdx.x;   // 0..8191
  const int b = row >> 10;
  const int i = row & 1023;
  const int L = icl[b] + 1;
  float rv = 0.f;
  int bad = 0;
  if (i < L) {
    const float* p = part + (size_t)row * 40;
    const int ns = (L + 127) >> 7;           // valid slots
    float m = -1e30f;
    for (int s = 0; s < ns; s++) m = fmaxf(m, p[s * 5 + 0]);
    float den = 0.f, msum = 0.f, cnt = 0.f, badf = 0.f;
    for (int s = 0; s < ns; s++) {
      den  += p[s * 5 + 1] * __expf(p[s * 5 + 0] - m);
      msum += p[s * 5 + 2];
      cnt  += p[s * 5 + 3];
      badf  = fmaxf(badf, p[s * 5 + 4]);
    }
    const float A = msum - cnt * m;          // sum mask*(s - mx)
    const float mlpp = (A - cnt * __logf(den + 1e-6f)) / (cnt + 1e-6f);
    rv = -mlpp / (float)L;
    bad = badf > 0.f ? 1 : 0;
  }
  const int tid  = threadIdx.x;
  const int lane = tid & 63;
  const int wave = tid >> 6;
  for (int o = 32; o > 0; o >>= 1) rv += __shfl_down(rv, o, 64);
  const int wbad = (__ballot(bad) != 0ull) ? 1 : 0;
  __shared__ float sred[4];
  __shared__ int bred[4];
  if (lane == 0) { sred[wave] = rv; bred[wave] = wbad; }
  __syncthreads();
  if (tid == 0) {
    blk_sum[blk] = sred[0] + sred[1] + sred[2] + sred[3];
    blk_bad[blk] = bred[0] | bred[1] | bred[2] | bred[3];
  }
}

// ---------------- finalize (single wave, deterministic) ----------------
__global__ __launch_bounds__(64) void final_kernel(const float* __restrict__ blk_sum,
                                                   const int* __restrict__ blk_bad,
                                                   float* __restrict__ out) {
  const int tid = threadIdx.x;
  float v = (tid < 32) ? blk_sum[tid] : 0.f;
  for (int o = 32; o > 0; o >>= 1) v += __shfl_down(v, o, 64);
  if (tid == 0) {
    int vcount = 0;
    for (int bb = 0; bb < B_DIM; bb++) {
      const int any = blk_bad[bb * 4] | blk_bad[bb * 4 + 1] |
                      blk_bad[bb * 4 + 2] | blk_bad[bb * 4 + 3];
      vcount += any ? 1 : 0;
    }
    out[0] = v / fmaxf((float)vcount, 1.0f);
  }
}

extern "C" void kernel_launch(void* const* d_in, const int* in_sizes, int n_in,
                              void* d_out, int out_size, void* d_ws, size_t ws_size,
                              hipStream_t stream) {
  const float* feat = (const float*)d_in[0];
  const float* mask = (const float*)d_in[1];
  const int*   icl  = (const int*)d_in[2];
  float* out = (float*)d_out;

  char* ws = (char*)d_ws;
  __hip_bfloat16* Fb = (__hip_bfloat16*)ws;                 // 16 MiB
  float* part    = (float*)(ws + (16u << 20));              // 1.31 MiB
  float* blk_sum = (float*)(ws + (18u << 20));              // 128 B
  int*   blk_bad = (int*)(ws + (18u << 20) + 512);          // 128 B

  convert_kernel<<<dim3(8192), dim3(256), 0, stream>>>(feat, Fb);
  fused_kernel<<<dim3(8, 8, 8), dim3(512), 0, stream>>>(Fb, mask, icl, part);
  reduce_kernel<<<dim3(32), dim3(256), 0, stream>>>(part, icl, blk_sum, blk_bad);
  final_kernel<<<dim3(1), dim3(64), 0, stream>>>(blk_sum, blk_bad, out);
}